// Round 4
// baseline (61.008 us; speedup 1.0000x reference)
//
#include <hip/hip_runtime.h>

#define NFEAT 32
#define NCLS  8
#define NCUT  7   // N_CLASSES - 1

typedef float f32x4 __attribute__((ext_vector_type(4)));

__device__ __forceinline__ float row_prob(f32x4 v, f32x4 b, float cutv, int s)
{
    // partial dot product of this lane's 4 features
    float part = fmaf(v.x, b.x, fmaf(v.y, b.y, fmaf(v.z, b.z, v.w * b.w)));
    // reduce across the 8-lane group -> full eta, broadcast to all 8 lanes
    part += __shfl_xor(part, 1, 8);
    part += __shfl_xor(part, 2, 8);
    part += __shfl_xor(part, 4, 8);
    const float eta = part;

    float cum;
    if (s < NCUT) {
        float lp = fminf(fmaxf(cutv - eta, -30.f), 30.f);
        cum = 1.f - __expf(-__expf(lp));   // cloglog link
    } else {
        cum = 1.f;
    }

    // first difference along class axis
    float prev = __shfl_up(cum, 1, 8);
    if (s == 0) prev = 0.f;
    float p = cum - prev;
    return fminf(fmaxf(p, 1e-9f), 1.f - 1e-9f);
}

__global__ __launch_bounds__(256) void cloglog_probs_kernel(
    const float* __restrict__ X,
    const float* __restrict__ intercepts,
    const float* __restrict__ beta,
    float* __restrict__ out,
    long long n)   // number of rows
{
    const int t = threadIdx.x;
    const int s = t & 7;          // slot within the 8-lane row-group

    // Per-lane rank-select: cutv = s-th smallest intercept.
    // intercepts[] loads are wave-uniform -> SGPRs; ranks are SALU; only the
    // final select is per-lane. No LDS, no barrier.
    float c[NCUT];
    #pragma unroll
    for (int j = 0; j < NCUT; ++j) c[j] = intercepts[j];
    float cutv = c[0];
    #pragma unroll
    for (int i = 0; i < NCUT; ++i) {
        int r = 0;
        #pragma unroll
        for (int j = 0; j < NCUT; ++j)
            r += (c[j] < c[i]) || (c[j] == c[i] && j < i);  // index tie-break
        if (r == s) cutv = c[i];
    }

    // this lane's beta fragment (features 4s..4s+3)
    const f32x4 b = reinterpret_cast<const f32x4*>(beta)[s];

    const long long group   = ((long long)blockIdx.x * blockDim.x + t) >> 3;
    const long long ngroups = ((long long)gridDim.x * blockDim.x) >> 3;
    const f32x4* Xv = reinterpret_cast<const f32x4*>(X);

    long long row = group;
    // unroll-by-2: both non-temporal loads in flight before either compute
    for (; row + ngroups < n; row += 2 * ngroups) {
        const long long r1 = row + ngroups;
        f32x4 v0 = __builtin_nontemporal_load(&Xv[row * 8 + s]);
        f32x4 v1 = __builtin_nontemporal_load(&Xv[r1 * 8 + s]);

        float p0 = row_prob(v0, b, cutv, s);
        float p1 = row_prob(v1, b, cutv, s);

        __builtin_nontemporal_store(p0, &out[row * 8 + s]);
        __builtin_nontemporal_store(p1, &out[r1 * 8 + s]);
    }
    for (; row < n; row += ngroups) {
        f32x4 v = __builtin_nontemporal_load(&Xv[row * 8 + s]);
        float p = row_prob(v, b, cutv, s);
        __builtin_nontemporal_store(p, &out[row * 8 + s]);
    }
}

extern "C" void kernel_launch(void* const* d_in, const int* in_sizes, int n_in,
                              void* d_out, int out_size, void* d_ws, size_t ws_size,
                              hipStream_t stream) {
    const float* X          = (const float*)d_in[0];
    const float* intercepts = (const float*)d_in[1];
    const float* beta       = (const float*)d_in[2];
    float* out              = (float*)d_out;

    const long long n = (long long)in_sizes[0] / NFEAT;  // 2,000,000 rows

    const int block = 256;   // 32 row-groups per block
    int grid = 2048;         // 8 resident blocks/CU, grid-stride
    long long groups_needed = (n + 31) / 32;
    if (groups_needed < grid) grid = (int)groups_needed;

    cloglog_probs_kernel<<<grid, block, 0, stream>>>(X, intercepts, beta, out, n);
}

// Round 5
// 51.120 us; speedup vs baseline: 1.1934x; 1.1934x over previous
//
#include <hip/hip_runtime.h>

#define NFEAT 32
#define NCLS  8
#define NCUT  7   // N_CLASSES - 1

__global__ __launch_bounds__(256) void cloglog_probs_kernel(
    const float* __restrict__ X,
    const float* __restrict__ intercepts,
    const float* __restrict__ beta,
    float* __restrict__ out,
    long long n)   // number of rows
{
    __shared__ float s_cut[NCUT];

    const int t = threadIdx.x;
    if (t == 0) {
        float c[NCUT];
        #pragma unroll
        for (int a = 0; a < NCUT; ++a) c[a] = intercepts[a];
        // selection sort, 7 elements
        #pragma unroll
        for (int a = 0; a < NCUT; ++a)
            #pragma unroll
            for (int b = a + 1; b < NCUT; ++b)
                if (c[b] < c[a]) { float tmp = c[a]; c[a] = c[b]; c[b] = tmp; }
        #pragma unroll
        for (int a = 0; a < NCUT; ++a) s_cut[a] = c[a];
    }
    __syncthreads();

    const int s = t & 7;          // slot within 8-lane row-group
    // this lane's beta fragment (features 4s..4s+3) — uniform per slot, L1-resident
    const float4 b = reinterpret_cast<const float4*>(beta)[s];
    const float cutv = s_cut[s < NCUT ? s : 0];   // lane 7's value unused

    const long long group   = ((long long)blockIdx.x * blockDim.x + t) >> 3;
    const long long ngroups = ((long long)gridDim.x * blockDim.x) >> 3;

    for (long long row = group; row < n; row += ngroups) {
        // wave-contiguous float4 load (cached — X should stay LLC-resident)
        const float4 v = reinterpret_cast<const float4*>(X)[row * 8 + s];

        float part = fmaf(v.x, b.x, fmaf(v.y, b.y, fmaf(v.z, b.z, v.w * b.w)));
        // reduce across the 8-lane group -> full dot product eta
        part += __shfl_xor(part, 1, 8);
        part += __shfl_xor(part, 2, 8);
        part += __shfl_xor(part, 4, 8);
        const float eta = part;

        float cum;
        if (s < NCUT) {
            float lp = fminf(fmaxf(cutv - eta, -30.f), 30.f);
            cum = 1.f - __expf(-__expf(lp));   // cloglog link
        } else {
            cum = 1.f;
        }

        // first difference along the class axis
        float prev = __shfl_up(cum, 1, 8);
        if (s == 0) prev = 0.f;
        float p = cum - prev;
        p = fminf(fmaxf(p, 1e-9f), 1.f - 1e-9f);

        // non-temporal: keep the out stream from evicting X in the LLC
        __builtin_nontemporal_store(p, &out[row * 8 + s]);
    }
}

extern "C" void kernel_launch(void* const* d_in, const int* in_sizes, int n_in,
                              void* d_out, int out_size, void* d_ws, size_t ws_size,
                              hipStream_t stream) {
    const float* X          = (const float*)d_in[0];
    const float* intercepts = (const float*)d_in[1];
    const float* beta       = (const float*)d_in[2];
    float* out              = (float*)d_out;

    const long long n = (long long)in_sizes[0] / NFEAT;  // 2,000,000 rows

    const int block = 256;                 // 32 row-groups per block
    long long groups_needed = (n + 31) / 32;
    int grid = (int)(groups_needed < 2048 ? groups_needed : 2048);  // 8 blocks/CU

    cloglog_probs_kernel<<<grid, block, 0, stream>>>(X, intercepts, beta, out, n);
}